// Round 1
// baseline (341.114 us; speedup 1.0000x reference)
//
#include <hip/hip_runtime.h>
#include <math.h>

namespace {

constexpr int SEQ   = 2048;
constexpr int DH    = 64;
constexpr int QBLK  = 64;
constexpr int KVBLK = 64;
constexpr int NW    = 4;    // waves per block
constexpr int PAD   = 72;   // LDS leading-dim pad: 72 bf16 = 144 B (breaks 128B-stride bank conflict, keeps 16B align)
constexpr int BH    = 64;   // B*H = 4*16

typedef __bf16 bf16x8 __attribute__((ext_vector_type(8)));
typedef float  f32x4  __attribute__((ext_vector_type(4)));

union Frag8 {
  bf16x8 b;
  unsigned short u[8];
};

// fp32 -> bf16 round-to-nearest-even (bit twiddle; inputs are finite randn)
__device__ __forceinline__ unsigned short f2bf(float f) {
  union { float f; unsigned u; } v; v.f = f;
  unsigned r = v.u + 0x7fffu + ((v.u >> 16) & 1u);
  return (unsigned short)(r >> 16);
}

__global__ __launch_bounds__(256)
void attn_fwd(const float* __restrict__ Qg, const float* __restrict__ Kg,
              const float* __restrict__ Vg, float* __restrict__ Og)
{
  const int qt   = blockIdx.x;      // q-tile index, 0..31
  const int bh   = blockIdx.y;      // 0..63
  const int qb   = qt * QBLK;
  const int tid  = threadIdx.x;
  const int wv   = tid >> 6;        // wave 0..3
  const int lane = tid & 63;
  const int l16  = lane & 15;
  const int lhi  = lane >> 4;       // 0..3

  const size_t base = (size_t)bh * SEQ * DH;
  const float* Qp = Qg + base;
  const float* Kp = Kg + base;
  const float* Vp = Vg + base;
  float*       Op = Og + base;

  // K tile row-major [j][d]; V tile transposed [d][j]; P per-wave [qrow][j]
  __shared__ __align__(16) unsigned short K_lds [KVBLK][PAD];
  __shared__ __align__(16) unsigned short Vt_lds[DH   ][PAD];
  __shared__ __align__(16) unsigned short P_lds [NW][16][PAD];

  // ---- Q fragments, held in registers all kernel ----
  // A-frag layout: lane holds A[lane%16][8*(lane/16)+i]
  Frag8 aq[2];
  {
    const int qrowA = qb + wv*16 + l16;
    const float* src = Qp + (size_t)qrowA*DH + lhi*8;
#pragma unroll
    for (int kk = 0; kk < 2; ++kk) {
      float4 f0 = *(const float4*)(src + kk*32);
      float4 f1 = *(const float4*)(src + kk*32 + 4);
      aq[kk].u[0]=f2bf(f0.x); aq[kk].u[1]=f2bf(f0.y);
      aq[kk].u[2]=f2bf(f0.z); aq[kk].u[3]=f2bf(f0.w);
      aq[kk].u[4]=f2bf(f1.x); aq[kk].u[5]=f2bf(f1.y);
      aq[kk].u[6]=f2bf(f1.z); aq[kk].u[7]=f2bf(f1.w);
    }
  }

  f32x4 oacc[4];                       // [d-subtile]; C/D layout row=(lhi*4+r), col=dt*16+l16
#pragma unroll
  for (int dt = 0; dt < 4; ++dt) { f32x4 z = {0.f,0.f,0.f,0.f}; oacc[dt] = z; }
  float mrun[4] = {-INFINITY,-INFINITY,-INFINITY,-INFINITY};
  float lrun[4] = {0.f,0.f,0.f,0.f};

  const float scale = 0.125f;          // 1/sqrt(64)

  for (int t = 0; t <= qt; ++t) {
    const int kvb = t * KVBLK;

    __syncthreads();                   // prev iteration's readers done before overwrite
    // ---- stage K (row-major bf16) and V (transposed bf16) ----
#pragma unroll
    for (int i = 0; i < 4; ++i) {
      const int f   = tid + i*256;     // 0..1023 : 64 rows x 16 float4-chunks
      const int row = f >> 4;
      const int c4  = f & 15;
      const float4 kf = *(const float4*)(Kp + (size_t)(kvb+row)*DH + c4*4);
      short4 ks;
      ks.x=(short)f2bf(kf.x); ks.y=(short)f2bf(kf.y);
      ks.z=(short)f2bf(kf.z); ks.w=(short)f2bf(kf.w);
      *reinterpret_cast<short4*>(&K_lds[row][c4*4]) = ks;
      const float4 vf = *(const float4*)(Vp + (size_t)(kvb+row)*DH + c4*4);
      Vt_lds[c4*4+0][row] = f2bf(vf.x);
      Vt_lds[c4*4+1][row] = f2bf(vf.y);
      Vt_lds[c4*4+2][row] = f2bf(vf.z);
      Vt_lds[c4*4+3][row] = f2bf(vf.w);
    }
    __syncthreads();

    // ---- QK^T: wave's 16 rows x 64 cols, K-dim 64 in 2 MFMA steps ----
    f32x4 s[4];
#pragma unroll
    for (int jt = 0; jt < 4; ++jt) { f32x4 z = {0.f,0.f,0.f,0.f}; s[jt] = z; }
#pragma unroll
    for (int kk = 0; kk < 2; ++kk) {
#pragma unroll
      for (int jt = 0; jt < 4; ++jt) {
        bf16x8 bk = *(const bf16x8*)&K_lds[jt*16 + l16][kk*32 + lhi*8];
        s[jt] = __builtin_amdgcn_mfma_f32_16x16x32_bf16(aq[kk].b, bk, s[jt], 0, 0, 0);
      }
    }

    // ---- scale + causal mask (diag tile only) + online softmax ----
    const bool diag = (t == qt);
    float pv[4][4];                    // [jt][r]
    float mt[4] = {-INFINITY,-INFINITY,-INFINITY,-INFINITY};
#pragma unroll
    for (int jt = 0; jt < 4; ++jt) {
#pragma unroll
      for (int r = 0; r < 4; ++r) {
        float sc = s[jt][r] * scale;
        if (diag) {
          const int col = jt*16 + l16;
          const int row = wv*16 + lhi*4 + r;
          if (col > row) sc = -INFINITY;
        }
        pv[jt][r] = sc;
        mt[r] = fmaxf(mt[r], sc);
      }
    }
#pragma unroll
    for (int r = 0; r < 4; ++r) {
#pragma unroll
      for (int m = 1; m < 16; m <<= 1) mt[r] = fmaxf(mt[r], __shfl_xor(mt[r], m));
    }

    float fac[4];
#pragma unroll
    for (int r = 0; r < 4; ++r) {
      const float mnew = fmaxf(mrun[r], mt[r]);
      fac[r]  = __expf(mrun[r] - mnew);   // exp(-inf)=0 on first tile
      mrun[r] = mnew;
      lrun[r] *= fac[r];
    }
#pragma unroll
    for (int dt = 0; dt < 4; ++dt) {
#pragma unroll
      for (int r = 0; r < 4; ++r) oacc[dt][r] *= fac[r];
    }

    float ls[4] = {0.f,0.f,0.f,0.f};
#pragma unroll
    for (int jt = 0; jt < 4; ++jt) {
#pragma unroll
      for (int r = 0; r < 4; ++r) {
        const float p = __expf(pv[jt][r] - mrun[r]);   // exp(-inf - m) = 0 for masked
        ls[r] += p;
        P_lds[wv][lhi*4 + r][jt*16 + l16] = f2bf(p);
      }
    }
#pragma unroll
    for (int r = 0; r < 4; ++r) {
#pragma unroll
      for (int m = 1; m < 16; m <<= 1) ls[r] += __shfl_xor(ls[r], m);
      lrun[r] += ls[r];
    }

    // ---- PV: O[16][64] += P[16][64] * V[64][64] ----
    // (per-wave P_lds write->read: same array, compiler orders via lgkmcnt)
#pragma unroll
    for (int jj = 0; jj < 2; ++jj) {
      bf16x8 ap = *(const bf16x8*)&P_lds[wv][l16][jj*32 + lhi*8];
#pragma unroll
      for (int dt = 0; dt < 4; ++dt) {
        bf16x8 bv = *(const bf16x8*)&Vt_lds[dt*16 + l16][jj*32 + lhi*8];
        oacc[dt] = __builtin_amdgcn_mfma_f32_16x16x32_bf16(ap, bv, oacc[dt], 0, 0, 0);
      }
    }
  }

  // ---- epilogue: normalize by row sum, store fp32 ----
  const int orow = qb + wv*16 + lhi*4;
#pragma unroll
  for (int r = 0; r < 4; ++r) {
    const float inv = 1.0f / lrun[r];
    float* dst = Op + (size_t)(orow + r)*DH + l16;
#pragma unroll
    for (int dt = 0; dt < 4; ++dt) dst[dt*16] = oacc[dt][r] * inv;
  }
}

} // anonymous namespace

extern "C" void kernel_launch(void* const* d_in, const int* in_sizes, int n_in,
                              void* d_out, int out_size, void* d_ws, size_t ws_size,
                              hipStream_t stream) {
  const float* Q = (const float*)d_in[0];
  const float* K = (const float*)d_in[1];
  const float* V = (const float*)d_in[2];
  // d_in[3] is the causal tril mask — deterministic, handled analytically in-kernel.
  float* O = (float*)d_out;
  dim3 grid(SEQ / QBLK, BH);
  attn_fwd<<<grid, dim3(NW * 64), 0, stream>>>(Q, K, V, O);
}

// Round 2
// 132.584 us; speedup vs baseline: 2.5728x; 2.5728x over previous
//
#include <hip/hip_runtime.h>
#include <math.h>

namespace {

constexpr int SEQ   = 2048;
constexpr int DH    = 64;
constexpr int QBLK  = 64;
constexpr int KVBLK = 64;
constexpr int NQT   = SEQ / QBLK;   // 32
constexpr int PAD   = 72;           // bf16 elems per LDS row (144 B)

typedef __bf16 bf16x8 __attribute__((ext_vector_type(8)));
typedef float  f32x4  __attribute__((ext_vector_type(4)));

union FragA { bf16x8 v; unsigned u[4]; __bf16 h[8]; };

__device__ __forceinline__ unsigned pack2(float a, float b) {
  union { __bf16 h[2]; unsigned u; } x;
  x.h[0] = (__bf16)a; x.h[1] = (__bf16)b;
  return x.u;
}

__global__ __launch_bounds__(256, 4)
void attn_fwd(const float* __restrict__ Qg, const float* __restrict__ Kg,
              const float* __restrict__ Vg, float* __restrict__ Og)
{
  // XCD-aware decode: xcd = li&7 -> bh group pinned per XCD; qi descending
  // within each XCD stream so big (qi=31) blocks launch first.
  const int li  = blockIdx.x;
  const int xcd = li & 7;
  const int rem = li >> 3;              // 0..255
  const int qi  = NQT - 1 - (rem & 31); // 31..0
  const int bh  = xcd + 8 * (rem >> 5); // 0..63

  const int tid  = threadIdx.x;
  const int wv   = tid >> 6;
  const int lane = tid & 63;
  const int l16  = lane & 15;
  const int lhi  = lane >> 4;

  const int qb = qi * QBLK;
  const size_t base = (size_t)bh * SEQ * DH;
  const float* Qp = Qg + base;
  const float* Kp = Kg + base;
  const float* Vp = Vg + base;
  float*       Op = Og + base;

  // double-buffered K (row-major [kv][d]) and V^T ([d][kv]); no P_lds
  __shared__ __align__(16) __bf16 K_lds [2][KVBLK][PAD];
  __shared__ __align__(16) __bf16 Vt_lds[2][DH   ][PAD];

  // ---- Q fragments, pre-scaled by 1/sqrt(64)=0.125 (exact in bf16) ----
  // B-frag pattern: lane holds Q[q=l16][kd = kk*32 + lhi*8 + e]
  FragA aq[2];
  {
    const float* qsrc = Qp + (size_t)(qb + wv*16 + l16) * DH + lhi*8;
#pragma unroll
    for (int kk = 0; kk < 2; ++kk) {
      float4 a = *(const float4*)(qsrc + kk*32);
      float4 b = *(const float4*)(qsrc + kk*32 + 4);
      aq[kk].h[0]=(__bf16)(a.x*0.125f); aq[kk].h[1]=(__bf16)(a.y*0.125f);
      aq[kk].h[2]=(__bf16)(a.z*0.125f); aq[kk].h[3]=(__bf16)(a.w*0.125f);
      aq[kk].h[4]=(__bf16)(b.x*0.125f); aq[kk].h[5]=(__bf16)(b.y*0.125f);
      aq[kk].h[6]=(__bf16)(b.z*0.125f); aq[kk].h[7]=(__bf16)(b.w*0.125f);
    }
  }

  // ---- staging registers (prefetch depth 1) ----
  float4 kr[4];
  float  vr[16];
  const int vd   = lane;     // V column this thread handles
  const int vkv0 = wv * 16;  // V rows this thread handles

  auto load_tile = [&](int t) {
    const int kvb = t * KVBLK;
#pragma unroll
    for (int i = 0; i < 4; ++i) {
      const int f = tid + i*256, row = f >> 4, c4 = f & 15;
      kr[i] = *(const float4*)(Kp + (size_t)(kvb + row)*DH + c4*4);
    }
#pragma unroll
    for (int r = 0; r < 16; ++r)      // column read: coalesced across lanes
      vr[r] = Vp[(size_t)(kvb + vkv0 + r)*DH + vd];
  };

  auto store_tile = [&](int b) {
#pragma unroll
    for (int i = 0; i < 4; ++i) {
      const int f = tid + i*256, row = f >> 4, c4 = f & 15;
      uint2 w; w.x = pack2(kr[i].x, kr[i].y); w.y = pack2(kr[i].z, kr[i].w);
      *reinterpret_cast<uint2*>(&K_lds[b][row][c4*4]) = w;
    }
    uint4 w0, w1;
    w0.x = pack2(vr[0], vr[1]);   w0.y = pack2(vr[2], vr[3]);
    w0.z = pack2(vr[4], vr[5]);   w0.w = pack2(vr[6], vr[7]);
    w1.x = pack2(vr[8], vr[9]);   w1.y = pack2(vr[10], vr[11]);
    w1.z = pack2(vr[12], vr[13]); w1.w = pack2(vr[14], vr[15]);
    *reinterpret_cast<uint4*>(&Vt_lds[b][vd][vkv0])     = w0;
    *reinterpret_cast<uint4*>(&Vt_lds[b][vd][vkv0 + 8]) = w1;
  };

  f32x4 oacc[4];
#pragma unroll
  for (int dt = 0; dt < 4; ++dt) { f32x4 z = {0.f,0.f,0.f,0.f}; oacc[dt] = z; }
  float mrun = -INFINITY, lrun = 0.f;

  const int NT = qi + 1;
  load_tile(0);
  store_tile(0);
  __syncthreads();

  for (int t = 0; t < NT; ++t) {
    const int cur = t & 1;
    if (t + 1 < NT) load_tile(t + 1);   // global loads in flight during compute

    // ---- swapped QK^T: S^T[kv][q] = mfma(K-frag, Q-frag) ----
    f32x4 st[4];
#pragma unroll
    for (int jt = 0; jt < 4; ++jt) { f32x4 z = {0.f,0.f,0.f,0.f}; st[jt] = z; }
#pragma unroll
    for (int kk = 0; kk < 2; ++kk)
#pragma unroll
      for (int jt = 0; jt < 4; ++jt) {
        bf16x8 ak = *(const bf16x8*)&K_lds[cur][jt*16 + l16][kk*32 + lhi*8];
        st[jt] = __builtin_amdgcn_mfma_f32_16x16x32_bf16(ak, aq[kk].v, st[jt], 0, 0, 0);
      }

    // ---- online softmax; lane owns q = l16 (4-lane groups share a row) ----
    const bool diag = (t == qi);
    float p[4][4];
    float mt = -INFINITY;
#pragma unroll
    for (int jt = 0; jt < 4; ++jt)
#pragma unroll
      for (int r = 0; r < 4; ++r) {
        float s = st[jt][r];                       // kv_local = jt*16+lhi*4+r
        if (diag && (jt*16 + lhi*4 + r > wv*16 + l16)) s = -INFINITY;
        p[jt][r] = s;
        mt = fmaxf(mt, s);
      }
    mt = fmaxf(mt, __shfl_xor(mt, 16));
    mt = fmaxf(mt, __shfl_xor(mt, 32));
    const float mnew = fmaxf(mrun, mt);
    const float fac  = __expf(mrun - mnew);        // exp(-inf)=0 first tile
    mrun = mnew;

    float ls = 0.f;
#pragma unroll
    for (int jt = 0; jt < 4; ++jt)
#pragma unroll
      for (int r = 0; r < 4; ++r) {
        const float e = __expf(p[jt][r] - mnew);
        p[jt][r] = e;
        ls += e;
      }
    ls += __shfl_xor(ls, 16);
    ls += __shfl_xor(ls, 32);
    lrun = lrun * fac + ls;

    // rescale O: gather fac for this lane's accumulator rows (q' = lhi*4+r)
    float facr[4];
#pragma unroll
    for (int r = 0; r < 4; ++r) facr[r] = __shfl(fac, 20*lhi + r);
#pragma unroll
    for (int dt = 0; dt < 4; ++dt)
#pragma unroll
      for (int r = 0; r < 4; ++r) oacc[dt][r] *= facr[r];

    // ---- P^T (in-reg) -> P A-frag via pack + shuffle exchange ----
    unsigned pk[4][2];
#pragma unroll
    for (int jt = 0; jt < 4; ++jt) {
      pk[jt][0] = pack2(p[jt][0], p[jt][1]);
      pk[jt][1] = pack2(p[jt][2], p[jt][3]);
    }
    FragA pa[2];
#pragma unroll
    for (int kk = 0; kk < 2; ++kk)
#pragma unroll
      for (int j = 0; j < 4; ++j) {
        const int src = ((2*lhi + (j >> 1)) & 3) * 16 + l16;
        const int va = __shfl((int)pk[2*kk    ][j & 1], src);
        const int vb = __shfl((int)pk[2*kk + 1][j & 1], src);
        pa[kk].u[j] = (lhi & 2) ? (unsigned)vb : (unsigned)va;
      }

    // ---- PV: O[q][d] += P[q][kv] * V[kv][d] ----
#pragma unroll
    for (int kk = 0; kk < 2; ++kk)
#pragma unroll
      for (int dt = 0; dt < 4; ++dt) {
        bf16x8 bv = *(const bf16x8*)&Vt_lds[cur][dt*16 + l16][kk*32 + lhi*8];
        oacc[dt] = __builtin_amdgcn_mfma_f32_16x16x32_bf16(pa[kk].v, bv, oacc[dt], 0, 0, 0);
      }

    if (t + 1 < NT) store_tile(cur ^ 1);  // waits vmcnt, writes other buffer
    __syncthreads();
  }

  // ---- epilogue: normalize; gather 1/l for this lane's rows ----
  const float linv = 1.0f / lrun;
  float lr[4];
#pragma unroll
  for (int r = 0; r < 4; ++r) lr[r] = __shfl(linv, 20*lhi + r);
#pragma unroll
  for (int r = 0; r < 4; ++r) {
    float* dst = Op + (size_t)(qb + wv*16 + lhi*4 + r) * DH + l16;
#pragma unroll
    for (int dt = 0; dt < 4; ++dt) dst[dt*16] = oacc[dt][r] * lr[r];
  }
}

} // anonymous namespace

extern "C" void kernel_launch(void* const* d_in, const int* in_sizes, int n_in,
                              void* d_out, int out_size, void* d_ws, size_t ws_size,
                              hipStream_t stream) {
  const float* Q = (const float*)d_in[0];
  const float* K = (const float*)d_in[1];
  const float* V = (const float*)d_in[2];
  // d_in[3]: causal tril mask — constant, handled analytically in-kernel.
  float* O = (float*)d_out;
  attn_fwd<<<dim3(NQT * 64), dim3(256), 0, stream>>>(Q, K, V, O);
}

// Round 3
// 108.526 us; speedup vs baseline: 3.1432x; 1.2217x over previous
//
#include <hip/hip_runtime.h>
#include <math.h>

namespace {

constexpr int SEQ   = 2048;
constexpr int DH    = 64;
constexpr int KVBLK = 64;
constexpr int QW    = 64;            // q rows per wave
constexpr int NWAVE = 4;
constexpr int QBLK  = QW * NWAVE;    // 256
constexpr int NQB   = SEQ / QBLK;    // 8
constexpr int BH    = 64;            // B*H
constexpr int PADB  = 72;            // bf16 elems per LDS row (144 B)

typedef __bf16 bf16x8 __attribute__((ext_vector_type(8)));
typedef float  f32x16 __attribute__((ext_vector_type(16)));

union FragB { bf16x8 v; unsigned u[4]; __bf16 h[8]; };

__device__ __forceinline__ unsigned pack2(float a, float b) {
  union { __bf16 h[2]; unsigned u; } x;
  x.h[0] = (__bf16)a; x.h[1] = (__bf16)b;
  return x.u;
}

// (x,y) = permlane32_swap(a,b): x = {lo: a_own, hi: b_from(l-32)},
//                               y = {lo: a_from(l+32), hi: b_own}
__device__ __forceinline__ void swap32(int a, int b, int &x, int &y) {
#if __has_builtin(__builtin_amdgcn_permlane32_swap)
  auto r = __builtin_amdgcn_permlane32_swap(a, b, false, false);
  x = r[0]; y = r[1];
#else
  const bool hi = ((threadIdx.x & 63) >= 32);
  const int sa = __shfl_xor(a, 32), sb = __shfl_xor(b, 32);
  x = hi ? sb : a;
  y = hi ? b  : sa;
#endif
}

__device__ __forceinline__ float xhalf_max(float v) {
  int x, y; swap32(__float_as_int(v), __float_as_int(v), x, y);
  return fmaxf(__int_as_float(x), __int_as_float(y));
}
__device__ __forceinline__ float xhalf_sum(float v) {
  int x, y; swap32(__float_as_int(v), __float_as_int(v), x, y);
  return __int_as_float(x) + __int_as_float(y);
}

__global__ __launch_bounds__(256, 2)
void attn_fwd(const float* __restrict__ Qg, const float* __restrict__ Kg,
              const float* __restrict__ Vg, float* __restrict__ Og)
{
  // decode: xcd-pinned bh groups, big q-blocks first
  const int b   = blockIdx.x;
  const int xcd = b & 7;
  const int idx = b >> 3;                   // 0..63
  const int qi  = (NQB - 1) - (idx >> 3);   // 7..0
  const int bh  = xcd + 8 * (idx & 7);      // 0..63
  const int qb  = qi * QBLK;
  const int qb64 = qb >> 6;

  const int tid  = threadIdx.x;
  const int wv   = tid >> 6;
  const int lane = tid & 63;
  const int l31  = lane & 31;
  const int hi   = lane >> 5;

  const size_t base = (size_t)bh * SEQ * DH;
  const float* Qp = Qg + base;
  const float* Kp = Kg + base;
  const float* Vp = Vg + base;
  float*       Op = Og + base;

  // one smem slab: [0,18432) = K [2][64][72] bf16 ; [18432,36864) = V^T [2][64][72]
  __shared__ __align__(16) unsigned char smem[36864];
  auto K_lds  = reinterpret_cast<__bf16(*)[KVBLK][PADB]>(smem);
  auto Vt_lds = reinterpret_cast<__bf16(*)[DH][PADB]>(smem + 18432);

  // ---- Q B-frags: B[k=8*hi+e][q=l31] = Q[q][d=16ks+8hi+e] * 0.125*log2(e) ----
  const float qscale = 0.125f * 1.44269504088896f;
  FragB bq[2][4];
  const int wq0 = wv * QW;
  {
#pragma unroll
    for (int qt = 0; qt < 2; ++qt) {
      const float* src = Qp + (size_t)(qb + wq0 + qt*32 + l31) * DH + hi*8;
#pragma unroll
      for (int ks = 0; ks < 4; ++ks) {
        float4 f0 = *(const float4*)(src + ks*16);
        float4 f1 = *(const float4*)(src + ks*16 + 4);
        FragB f;
        f.h[0]=(__bf16)(f0.x*qscale); f.h[1]=(__bf16)(f0.y*qscale);
        f.h[2]=(__bf16)(f0.z*qscale); f.h[3]=(__bf16)(f0.w*qscale);
        f.h[4]=(__bf16)(f1.x*qscale); f.h[5]=(__bf16)(f1.y*qscale);
        f.h[6]=(__bf16)(f1.z*qscale); f.h[7]=(__bf16)(f1.w*qscale);
        bq[qt][ks] = f;
      }
    }
  }

  // ---- staging registers ----
  float4 kr[2][2];
  float  vr[16];
  const int kc8 = tid & 7;
  const int vd  = tid & 63;
  const int vk0 = (tid >> 6) * 16;

  auto load_tile = [&](int t) {
    const int kvb = t * KVBLK;
#pragma unroll
    for (int p = 0; p < 2; ++p) {
      const float* s = Kp + (size_t)(kvb + 32*p + (tid >> 3)) * DH + kc8*8;
      kr[p][0] = *(const float4*)s;
      kr[p][1] = *(const float4*)(s + 4);
    }
#pragma unroll
    for (int r = 0; r < 16; ++r)
      vr[r] = Vp[(size_t)(kvb + vk0 + r) * DH + vd];
  };

  auto store_tile = [&](int buf) {
#pragma unroll
    for (int p = 0; p < 2; ++p) {
      uint4 w;
      w.x = pack2(kr[p][0].x, kr[p][0].y); w.y = pack2(kr[p][0].z, kr[p][0].w);
      w.z = pack2(kr[p][1].x, kr[p][1].y); w.w = pack2(kr[p][1].z, kr[p][1].w);
      *reinterpret_cast<uint4*>(&K_lds[buf][32*p + (tid >> 3)][kc8*8]) = w;
    }
    uint4 w0, w1;
    w0.x = pack2(vr[0],  vr[1]);  w0.y = pack2(vr[2],  vr[3]);
    w0.z = pack2(vr[4],  vr[5]);  w0.w = pack2(vr[6],  vr[7]);
    w1.x = pack2(vr[8],  vr[9]);  w1.y = pack2(vr[10], vr[11]);
    w1.z = pack2(vr[12], vr[13]); w1.w = pack2(vr[14], vr[15]);
    *reinterpret_cast<uint4*>(&Vt_lds[buf][vd][vk0])     = w0;
    *reinterpret_cast<uint4*>(&Vt_lds[buf][vd][vk0 + 8]) = w1;
  };

  // ---- accumulators: O^T[d = 32dt+(r&3)+8(r>>2)+4hi][q = 32qt+l31] ----
  f32x16 oacc[2][2];
#pragma unroll
  for (int qt = 0; qt < 2; ++qt)
#pragma unroll
    for (int dt = 0; dt < 2; ++dt)
#pragma unroll
      for (int r = 0; r < 16; ++r) oacc[qt][dt][r] = 0.f;
  float mrun[2] = {-INFINITY, -INFINITY};
  float lrun[2] = {0.f, 0.f};

  const int NT = qb64 + 4;
  const int tmax_wave = qb64 + wv;

  load_tile(0);
  store_tile(0);
  __syncthreads();

  for (int t = 0; t < NT; ++t) {
    const int cur = t & 1;
    if (t + 1 < NT) load_tile(t + 1);

    if (t <= tmax_wave) {
      const bool diag = (t == tmax_wave);
      FragB pa[2][4];

#pragma unroll
      for (int qt = 0; qt < 2; ++qt) {
        f32x16 st[2];
#pragma unroll
        for (int T = 0; T < 2; ++T)
#pragma unroll
          for (int r = 0; r < 16; ++r) st[T][r] = 0.f;
        __builtin_amdgcn_s_setprio(1);
#pragma unroll
        for (int T = 0; T < 2; ++T)
#pragma unroll
          for (int ks = 0; ks < 4; ++ks) {
            bf16x8 ak = *(const bf16x8*)&K_lds[cur][T*32 + l31][ks*16 + hi*8];
            st[T] = __builtin_amdgcn_mfma_f32_32x32x16_bf16(ak, bq[qt][ks].v, st[T], 0, 0, 0);
          }
        __builtin_amdgcn_s_setprio(0);

        float p[2][16];
        float mt = -INFINITY;
#pragma unroll
        for (int T = 0; T < 2; ++T)
#pragma unroll
          for (int r = 0; r < 16; ++r) {
            float s = st[T][r];
            if (diag) {
              const int kvl = T*32 + (r & 3) + 4*hi + 8*(r >> 2);
              if (kvl > qt*32 + l31) s = -INFINITY;
            }
            p[T][r] = s;
            mt = fmaxf(mt, s);
          }
        mt = xhalf_max(mt);
        const float mnew = fmaxf(mrun[qt], mt);
        const float fac  = exp2f(mrun[qt] - mnew);
        mrun[qt] = mnew;

        float ls = 0.f;
#pragma unroll
        for (int T = 0; T < 2; ++T)
#pragma unroll
          for (int r = 0; r < 16; ++r) {
            const float e = exp2f(p[T][r] - mnew);
            p[T][r] = e;
            ls += e;
          }
        ls = xhalf_sum(ls);
        lrun[qt] = lrun[qt] * fac + ls;

#pragma unroll
        for (int dt = 0; dt < 2; ++dt)
#pragma unroll
          for (int r = 0; r < 16; ++r) oacc[qt][dt][r] *= fac;

        unsigned pk[2][8];
#pragma unroll
        for (int T = 0; T < 2; ++T)
#pragma unroll
          for (int j = 0; j < 8; ++j) pk[T][j] = pack2(p[T][2*j], p[T][2*j + 1]);

#pragma unroll
        for (int ks = 0; ks < 4; ++ks) {
          const int T  = ks >> 1;
          const int gA = (2*ks) & 3;
          const int gB = (2*ks + 1) & 3;
          int x0, y0, x1, y1;
          swap32((int)pk[T][2*gA],     (int)pk[T][2*gB],     x0, y0);
          swap32((int)pk[T][2*gA + 1], (int)pk[T][2*gB + 1], x1, y1);
          pa[qt][ks].u[0] = (unsigned)x0;
          pa[qt][ks].u[1] = (unsigned)x1;
          pa[qt][ks].u[2] = (unsigned)y0;
          pa[qt][ks].u[3] = (unsigned)y1;
        }
      }

      __builtin_amdgcn_s_setprio(1);
#pragma unroll
      for (int dt = 0; dt < 2; ++dt)
#pragma unroll
        for (int ks = 0; ks < 4; ++ks) {
          bf16x8 av = *(const bf16x8*)&Vt_lds[cur][dt*32 + l31][ks*16 + hi*8];
          oacc[0][dt] = __builtin_amdgcn_mfma_f32_32x32x16_bf16(av, pa[0][ks].v, oacc[0][dt], 0, 0, 0);
          oacc[1][dt] = __builtin_amdgcn_mfma_f32_32x32x16_bf16(av, pa[1][ks].v, oacc[1][dt], 0, 0, 0);
        }
      __builtin_amdgcn_s_setprio(0);
    }

    if (t + 1 < NT) store_tile(cur ^ 1);
    __syncthreads();
  }

  // ---- epilogue: O^T regs -> LDS transpose (normalized) -> coalesced store ----
  const float linv[2] = {1.0f / lrun[0], 1.0f / lrun[1]};
  float* slabw = reinterpret_cast<float*>(smem) + (wv & 1) * (64 * 68);

#pragma unroll
  for (int round = 0; round < 2; ++round) {
    __syncthreads();
    if ((wv >> 1) == round) {
#pragma unroll
      for (int qt = 0; qt < 2; ++qt)
#pragma unroll
        for (int dt = 0; dt < 2; ++dt)
#pragma unroll
          for (int g = 0; g < 4; ++g) {
            float4 w;
            w.x = oacc[qt][dt][4*g + 0] * linv[qt];
            w.y = oacc[qt][dt][4*g + 1] * linv[qt];
            w.z = oacc[qt][dt][4*g + 2] * linv[qt];
            w.w = oacc[qt][dt][4*g + 3] * linv[qt];
            *(float4*)&slabw[(qt*32 + l31)*68 + dt*32 + 8*g + 4*hi] = w;
          }
    }
    __syncthreads();
    if ((wv >> 1) == round) {
      const float* slabr = reinterpret_cast<const float*>(smem) + (wv & 1) * (64 * 68);
      float* dst = Op + (size_t)(qb + wq0) * DH;
#pragma unroll
      for (int i = 0; i < 16; ++i) {
        const int row = i*4 + (lane >> 4);
        const int ch  = lane & 15;
        float4 v = *(const float4*)&slabr[row*68 + ch*4];
        *(float4*)&dst[row*64 + ch*4] = v;
      }
    }
  }
}

} // anonymous namespace

extern "C" void kernel_launch(void* const* d_in, const int* in_sizes, int n_in,
                              void* d_out, int out_size, void* d_ws, size_t ws_size,
                              hipStream_t stream) {
  const float* Q = (const float*)d_in[0];
  const float* K = (const float*)d_in[1];
  const float* V = (const float*)d_in[2];
  // d_in[3]: causal tril mask — constant, handled analytically in-kernel.
  float* O = (float*)d_out;
  attn_fwd<<<dim3(NQB * BH), dim3(256), 0, stream>>>(Q, K, V, O);
}